// Round 10
// baseline (2734.662 us; speedup 1.0000x reference)
//
#include <hip/hip_runtime.h>
#include <hip/hip_bf16.h>
#include <math.h>

typedef __hip_bfloat16 bf16;
using s16x8 = __attribute__((ext_vector_type(8))) short;
using f32x4 = __attribute__((ext_vector_type(4))) float;
typedef __attribute__((address_space(1))) const unsigned int gu32;
typedef __attribute__((address_space(3))) unsigned int lu32;

#define RTOT 4096      // B*S rows
#define XCT  1056      // c,t input stride; layout [c(514) 0pad->528 | t(514) 0pad->1056]
#define TOFF 528       // t offset in Xct (16B-aligned: 528*2B = 1056B)
#define NT1  2176      // GEMM1 packed N (c cols 0..1027, t cols 1028..2055, pad ->2176)
#define HLD  2176      // H stride (2 nets x 1088)
#define KH   1088      // GEMM2 K padded (1028->1088)
#define CLD  640       // c/t/fc/nc fp32 stride
#define NDC  512       // d+s hidden padded (257+128=385 -> 512)
#define KDP  576       // small-mlp K padded (514->576)
#define F2E  514
#define SP   512
#define YZS  16        // ybase split-K factor

__device__ __forceinline__ float gelu_ex(float x) {
    return 0.5f * x * (1.0f + erff(x * 0.70710678118654752f));
}
__device__ __forceinline__ float sigm(float x) { return 1.0f / (1.0f + expf(-x)); }
__device__ __forceinline__ unsigned short bfb(float x) {
    __hip_bfloat16 h = __float2bfloat16(x);
    return *(unsigned short*)&h;
}
__device__ __forceinline__ unsigned packbf(float x, float y) {
    return (unsigned)bfb(x) | ((unsigned)bfb(y) << 16);
}
__device__ __forceinline__ void glds16(const bf16* g, short* l) {
    __builtin_amdgcn_global_load_lds((gu32*)g, (lu32*)l, 16, 0, 0);
}

// ---------------- bf16 MFMA GEMM: C[M,N] = A[M,K] * Bt[N,K]^T (+bias, epilogue) ----
// 2-phase double-buffered staging: issue next tile's global_load_lds BEFORE compute;
// one __syncthreads per K-step (vmcnt(0) drain fences prefetch + LDS reuse).
// BNT=64 everywhere now (occupancy: 24KB LDS -> 5 blocks/CU; gemm1 grid 1088 blocks).
// EPI: 0 = x+bias, 1 = tanh(x+bias), 2 = gelu(x+bias)
template<int EPI, int BNT>
__global__ __launch_bounds__(256)
void gemm_bt(const bf16* __restrict__ A, int lda,
             const bf16* __restrict__ Bt, int ldb,
             float* __restrict__ C, int ldc,
             const float* __restrict__ bias, int bias_ld, int ktiles,
             long zA, long zB, long zC, long zBias)
{
    A    += (long)blockIdx.z * zA;
    Bt   += (long)blockIdx.z * zB;
    C    += (long)blockIdx.z * zC;
    bias += (long)blockIdx.z * zBias;

    constexpr int NC = BNT / 32;            // n-frags per wave (4 or 2)
    __shared__ __align__(16) short As[2][128 * 32];
    __shared__ __align__(16) short Bs[2][BNT * 32];
    const int tid  = threadIdx.x;
    const int lane = tid & 63;
    const int wave = tid >> 6;
    const int l15  = lane & 15, kl = lane >> 4;
    const long mb = (long)blockIdx.x * 128;
    const long nb = (long)blockIdx.y * BNT;
    const int wr = (wave >> 1) * 64;
    const int wc = (wave & 1) * (BNT / 2);

    f32x4 acc[4][NC] = {};

    const int grp_r = lane >> 2;            // 0..15
    const int gcol  = (lane & 3) * 8;       // shorts
    const bf16* gA0 = A  + (mb + wave * 32 + grp_r) * (long)lda + gcol;
    const bf16* gA1 = gA0 + 16 * (long)lda;
    const int brow0 = (BNT == 128) ? wave * 32 : wave * 16;
    const bf16* gB0 = Bt + (nb + brow0 + grp_r) * (long)ldb + gcol;
    const bf16* gB1 = gB0 + 16 * (long)ldb;  // only used when BNT==128

    auto stage = [&](int buf, int kt) {
        const long ko = (long)kt * 32;
        glds16(gA0 + ko, &As[buf][(wave * 32) * 32]);
        glds16(gA1 + ko, &As[buf][(wave * 32 + 16) * 32]);
        glds16(gB0 + ko, &Bs[buf][brow0 * 32]);
        if (BNT == 128) glds16(gB1 + ko, &Bs[buf][(brow0 + 16) * 32]);
    };

    stage(0, 0);
    __syncthreads();                        // prologue drain
    int cur = 0;
    for (int kt = 0; kt < ktiles; ++kt) {
        if (kt + 1 < ktiles) stage(cur ^ 1, kt + 1);   // prefetch flies under compute
        s16x8 af[4], bfr[NC];
#pragma unroll
        for (int m = 0; m < 4; ++m) {
            int ar = wr + m * 16 + l15;
            af[m] = *reinterpret_cast<const s16x8*>(&As[cur][ar * 32 + kl * 8]);
        }
#pragma unroll
        for (int n = 0; n < NC; ++n) {
            int br = wc + n * 16 + l15;
            bfr[n] = *reinterpret_cast<const s16x8*>(&Bs[cur][br * 32 + kl * 8]);
        }
#pragma unroll
        for (int m = 0; m < 4; ++m)
#pragma unroll
            for (int n = 0; n < NC; ++n)
                acc[m][n] = __builtin_amdgcn_mfma_f32_16x16x32_bf16(af[m], bfr[n], acc[m][n], 0, 0, 0);
        __syncthreads();                    // drains prefetch vmcnt + LDS reuse fence
        cur ^= 1;
    }

    const float* brow = bias + (bias_ld ? (long)(mb >> 9) * bias_ld : 0);
#pragma unroll
    for (int m = 0; m < 4; ++m) {
        const long grow0 = mb + wr + m * 16 + kl * 4;
#pragma unroll
        for (int n = 0; n < NC; ++n) {
            const long gcol2 = nb + wc + n * 16 + l15;
            const float bb = brow[gcol2];
            f32x4 v = acc[m][n];
#pragma unroll
            for (int r = 0; r < 4; ++r) {
                float x = v[r] + bb;
                if (EPI == 1) x = tanhf(x);
                else if (EPI == 2) x = gelu_ex(x);
                C[(grow0 + r) * (long)ldc + gcol2] = x;
            }
        }
    }
}

// ---------------- fp32 SGEMM (rfft/irfft tables): C[M,N] = A[M,K] * Bt[N,K]^T -------
__global__ __launch_bounds__(256)
void sgemm_bt(const float* __restrict__ A, int lda,
              const float* __restrict__ Bt, int ldb,
              float* __restrict__ C, int ldc, int ktiles)
{
    __shared__ float As[16][68];   // [k][m], 68 = 64 + 4 pad
    __shared__ float Bs[16][68];   // [k][n]
    const int tid = threadIdx.x;
    const int tx = tid & 15, ty = tid >> 4;
    const int lr = tid >> 2, lc = (tid & 3) * 4;     // load: row 0..63, col 4-chunk
    const long mb = (long)blockIdx.x * 64, nb = (long)blockIdx.y * 64;
    float acc[4][4] = {};
    const float* Ap = A  + (mb + lr) * (long)lda + lc;
    const float* Bp = Bt + (nb + lr) * (long)ldb + lc;
    for (int kt = 0; kt < ktiles; ++kt) {
        float4 av = *(const float4*)(Ap + kt * 16);
        float4 bv = *(const float4*)(Bp + kt * 16);
        __syncthreads();
        As[lc + 0][lr] = av.x; As[lc + 1][lr] = av.y;
        As[lc + 2][lr] = av.z; As[lc + 3][lr] = av.w;
        Bs[lc + 0][lr] = bv.x; Bs[lc + 1][lr] = bv.y;
        Bs[lc + 2][lr] = bv.z; Bs[lc + 3][lr] = bv.w;
        __syncthreads();
#pragma unroll
        for (int kk = 0; kk < 16; ++kk) {
            float4 a = *(const float4*)&As[kk][ty * 4];
            float4 b = *(const float4*)&Bs[kk][tx * 4];
            acc[0][0] = fmaf(a.x, b.x, acc[0][0]); acc[0][1] = fmaf(a.x, b.y, acc[0][1]);
            acc[0][2] = fmaf(a.x, b.z, acc[0][2]); acc[0][3] = fmaf(a.x, b.w, acc[0][3]);
            acc[1][0] = fmaf(a.y, b.x, acc[1][0]); acc[1][1] = fmaf(a.y, b.y, acc[1][1]);
            acc[1][2] = fmaf(a.y, b.z, acc[1][2]); acc[1][3] = fmaf(a.y, b.w, acc[1][3]);
            acc[2][0] = fmaf(a.z, b.x, acc[2][0]); acc[2][1] = fmaf(a.z, b.y, acc[2][1]);
            acc[2][2] = fmaf(a.z, b.z, acc[2][2]); acc[2][3] = fmaf(a.z, b.w, acc[2][3]);
            acc[3][0] = fmaf(a.w, b.x, acc[3][0]); acc[3][1] = fmaf(a.w, b.y, acc[3][1]);
            acc[3][2] = fmaf(a.w, b.z, acc[3][2]); acc[3][3] = fmaf(a.w, b.w, acc[3][3]);
        }
    }
#pragma unroll
    for (int i = 0; i < 4; ++i) {
        float4 st = { acc[i][0], acc[i][1], acc[i][2], acc[i][3] };
        *(float4*)&C[(mb + ty * 4 + i) * (long)ldc + nb + tx * 4] = st;
    }
}

// ---------------- setup kernels ----------------
__global__ void build_tables(float* __restrict__ RT, float* __restrict__ IT)
{
    long idx = (long)blockIdx.x * 256 + threadIdx.x;
    const double W = 6.283185307179586476925286766559005768 / 512.0;
    if (idx < 640L * 512) {                  // RT[640][512]: rfft rows (re/im interleaved)
        int r = (int)(idx >> 9), n = (int)(idx & 511);
        float v = 0.f;
        if (r < F2E) {
            int bin = r >> 1;
            int m = (bin * n) & 511;
            double ang = W * m;
            v = (r & 1) ? (float)(-sin(ang)) : (float)cos(ang);
        }
        RT[idx] = v;
    } else {
        long j2 = idx - 640L * 512;          // IT[512][640]: irfft rows
        if (j2 < 512L * 640) {
            int n = (int)(j2 / 640), j = (int)(j2 % 640);
            float v = 0.f;
            if (j < F2E) {
                int bin = j >> 1;
                int m = (bin * n) & 511;
                double ang = W * m;
                bool edge = (bin == 0 || bin == 256);
                double ck = edge ? 1.0 : 2.0;
                if (j & 1) v = edge ? 0.f : (float)(-ck * sin(ang) / 512.0);
                else       v = (float)(ck * cos(ang) / 512.0);
            }
            IT[j2] = v;
        }
    }
}

__global__ void build_damp(float* damp, const float* __restrict__ fd)
{
    int i = blockIdx.x * 256 + threadIdx.x;
    if (i < F2E) damp[i] = fd[i < 257 ? i : i - 257];   // torch repeat(...,2) tiling quirk
}

// split-K ybase partials
__global__ void ybase_part(const float* __restrict__ srcp, const float* __restrict__ tgtp,
                           const float* __restrict__ cw1, const float* __restrict__ tw1,
                           float* __restrict__ Yp)
{
    const int n = blockIdx.x * 256 + threadIdx.x;
    const int b = blockIdx.y, z = blockIdx.z;
    if (n >= NT1) return;
    float acc = 0.f;
    if (n < 2056) {
        const bool isT = (n >= 1028);
        const int nn = isT ? n - 1028 : n;
        const float* w = isT ? tw1 : cw1;
        const float* s = srcp + b * 513;
        const float* t = tgtp + b * 513;
        const int k0 = z * (512 / YZS);
        for (int k = k0; k < k0 + 512 / YZS; ++k) {
            acc = fmaf(s[k], w[(size_t)(1028 + k) * 1028 + nn], acc);
            acc = fmaf(t[k], w[(size_t)(1540 + k) * 1028 + nn], acc);
        }
    }
    Yp[((size_t)z * 8 + b) * NT1 + n] = acc;
}

__global__ void ybase_reduce(const float* __restrict__ Yp,
                             const float* __restrict__ cb1, const float* __restrict__ tb1,
                             float* __restrict__ Yb)
{
    const int n = blockIdx.x * 256 + threadIdx.x;
    const int b = blockIdx.y;
    if (n >= NT1) return;
    float acc = 0.f;
    if (n < 2056) acc = (n < 1028) ? cb1[n] : tb1[n - 1028];
    for (int z = 0; z < YZS; ++z) acc += Yp[((size_t)z * 8 + b) * NT1 + n];
    Yb[b * NT1 + n] = acc;
}

// W1ct[r][k] matching Xct's K layout: k<514 -> W1[k], 528<=k<1042 -> W1[514+k-528].
// Packed N: r<1028 c-net, 1028<=r<2056 t-net, else 0.
__global__ void w1prep(bf16* __restrict__ dst,
                       const float* __restrict__ cw1, const float* __restrict__ tw1)
{
    const int r = blockIdx.x;
    const int k = blockIdx.y * 256 + threadIdx.x;
    if (k >= XCT) return;
    float v = 0.f;
    if (r < 2056) {
        const float* w = (r < 1028) ? cw1 : tw1;
        const int nn = (r < 1028) ? r : r - 1028;
        int kk = -1;
        if (k < 514) kk = k;
        else if (k >= TOFF && k < TOFF + 514) kk = 514 + (k - TOFF);
        if (kk >= 0) v = w[(size_t)kk * 1028 + nn];
    }
    dst[(long)r * XCT + k] = __float2bfloat16(v);
}

// transpose fp32 [K,N] weights into bf16 [rows=ldn][cols=ldk], zero-padded, 2 segments
__global__ void wprep(bf16* __restrict__ dst, int ldk,
                      const float* s0, int K0, int N0, int r00,
                      const float* s1, int K1, int N1, int r01)
{
    int r = blockIdx.x;
    int k = blockIdx.y * 256 + threadIdx.x;
    if (k >= ldk) return;
    float v = 0.f;
    if (s0 && r >= r00 && r < r00 + N0 && k < K0) v = s0[(long)k * N0 + (r - r00)];
    if (s1 && r >= r01 && r < r01 + N1 && k < K1) v = s1[(long)k * N1 + (r - r01)];
    dst[(long)r * ldk + k] = __float2bfloat16(v);
}

__global__ void bias_fill(float* __restrict__ dst, int n,
                          const float* s0, int l0, int o0,
                          const float* s1, int l1, int o1)
{
    int i = blockIdx.x * 256 + threadIdx.x;
    if (i >= n) return;
    float v = 0.f;
    if (s0 && i >= o0 && i < o0 + l0) v = s0[i - o0];
    if (s1 && i >= o1 && i < o1 + l1) v = s1[i - o1];
    dst[i] = v;
}

// state -> Xct only (Cb/Tb eliminated: state is provably finite, nan_to_num = identity)
__global__ void initconv(const float* __restrict__ cb, const float* __restrict__ tb,
                         bf16* __restrict__ X)
{
    int row = blockIdx.x;
    for (int j = threadIdx.x; j < F2E; j += 256) {
        X[(long)row * XCT + j]        = __float2bfloat16(cb[(long)row * CLD + j]);
        X[(long)row * XCT + TOFF + j] = __float2bfloat16(tb[(long)row * CLD + j]);
    }
}

// zero the 2x14 K-pad columns of Xct once
__global__ void xpad_zero(bf16* __restrict__ X)
{
    int row = blockIdx.x;
    int t = threadIdx.x;                 // 32 threads; 28 used
    if (t < 28) {
        int j = (t < 14) ? (514 + t) : (TOFF + 514 + (t - 14));
        X[(long)row * XCT + j] = __float2bfloat16(0.f);
    }
}

// ---------------- per-step kernels (wave-per-row, vectorized) ----------------
__global__ __launch_bounds__(256)
void ln_gelu(const float* __restrict__ Y, bf16* __restrict__ H,
             const float* __restrict__ cg, const float* __restrict__ cbeta,
             const float* __restrict__ tg, const float* __restrict__ tbeta)
{
    const int lane = threadIdx.x & 63, wave = threadIdx.x >> 6;
    const int p = blockIdx.x * 4 + wave;      // 8192 (row,net) pairs
    const int row = p >> 1, net = p & 1;
    const float4* y4 = (const float4*)(Y + (long)row * NT1 + net * 1028);
    float4 v[4], vt = {0.f, 0.f, 0.f, 0.f};
    float s = 0.f;
#pragma unroll
    for (int k = 0; k < 4; ++k) {
        v[k] = y4[lane + k * 64];
        s += v[k].x + v[k].y + v[k].z + v[k].w;
    }
    if (lane == 0) { vt = y4[256]; s += vt.x + vt.y + vt.z + vt.w; }
#pragma unroll
    for (int o = 1; o < 64; o <<= 1) s += __shfl_xor(s, o, 64);
    const float mean = s * (1.0f / 1028.0f);
    float vs = 0.f;
#pragma unroll
    for (int k = 0; k < 4; ++k) {
        float a = v[k].x - mean, b = v[k].y - mean, c = v[k].z - mean, d = v[k].w - mean;
        vs += a * a + b * b + c * c + d * d;
    }
    if (lane == 0) {
        float a = vt.x - mean, b = vt.y - mean, c = vt.z - mean, d = vt.w - mean;
        vs += a * a + b * b + c * c + d * d;
    }
#pragma unroll
    for (int o = 1; o < 64; o <<= 1) vs += __shfl_xor(vs, o, 64);
    const float rs = rsqrtf(vs * (1.0f / 1028.0f) + 1e-5f);
    const float4* g4 = (const float4*)(net ? tg : cg);
    const float4* b4 = (const float4*)(net ? tbeta : cbeta);
    bf16* h = H + (long)row * HLD + (long)net * KH;
#pragma unroll
    for (int k = 0; k < 4; ++k) {
        int j = lane + k * 64;
        float4 gv = g4[j], bv = b4[j];
        ushort4 o;
        o.x = bfb(gelu_ex((v[k].x - mean) * rs * gv.x + bv.x));
        o.y = bfb(gelu_ex((v[k].y - mean) * rs * gv.y + bv.y));
        o.z = bfb(gelu_ex((v[k].z - mean) * rs * gv.z + bv.z));
        o.w = bfb(gelu_ex((v[k].w - mean) * rs * gv.w + bv.w));
        *(ushort4*)(&h[j * 4]) = o;
    }
    if (lane == 0) {
        float4 gv = g4[256], bv = b4[256];
        ushort4 o;
        o.x = bfb(gelu_ex((vt.x - mean) * rs * gv.x + bv.x));
        o.y = bfb(gelu_ex((vt.y - mean) * rs * gv.y + bv.y));
        o.z = bfb(gelu_ex((vt.z - mean) * rs * gv.z + bv.z));
        o.w = bfb(gelu_ex((vt.w - mean) * rs * gv.w + bv.w));
        *(ushort4*)(&h[1024]) = o;
    }
}

// fused heads + state update; per-block partials (NO atomics).
__global__ __launch_bounds__(256)
void fused_update(const float* __restrict__ Hd,
                  const float* __restrict__ dw2, const float* __restrict__ db2,
                  const float* __restrict__ sw2, const float* __restrict__ sb2,
                  const float* __restrict__ c, const float* __restrict__ t,
                  const float* __restrict__ fc, const float* __restrict__ ft,
                  float* __restrict__ nc, float* __restrict__ nt,
                  const float* __restrict__ damp,
                  const float* __restrict__ csc, const float* __restrict__ tsc,
                  float* __restrict__ part)
{
    __shared__ float red[16];
    const int tid = threadIdx.x, lane = tid & 63, wave = tid >> 6;
    const int row = blockIdx.x * 4 + wave;

    const float* hc = Hd + (long)row * NDC;
    const float* ht = Hd + (long)(4096 + row) * NDC;
    float s1 = 0.f, s2 = 0.f, s3 = 0.f;
#pragma unroll
    for (int k = 0; k < 4; ++k) {
        int j = lane + k * 64;
        s1 += hc[j] * dw2[j];
        s3 += ht[j] * dw2[j];
    }
    if (lane == 0) { s1 += hc[256] * dw2[256]; s3 += ht[256] * dw2[256]; }
#pragma unroll
    for (int k = 0; k < 2; ++k) {
        int j = lane + k * 64;
        s2 += hc[257 + j] * sw2[j];
    }
#pragma unroll
    for (int o = 1; o < 64; o <<= 1) {
        s1 += __shfl_xor(s1, o, 64);
        s2 += __shfl_xor(s2, o, 64);
        s3 += __shfl_xor(s3, o, 64);
    }
    float a  = sigm(s1 + db2[0]);
    float at = sigm(s3 + db2[0]);
    float g  = sigm(s2 + sb2[0]) + 0.5f;
    if (isnan(a))  a  = 0.f;
    if (isnan(at)) at = 0.f;
    const float gac = g * a  * csc[0];
    const float gat = g * at * tsc[0];

    const float2* c2  = (const float2*)(c  + (long)row * CLD);
    const float2* t2  = (const float2*)(t  + (long)row * CLD);
    const float2* fc2 = (const float2*)(fc + (long)row * CLD);
    const float2* ft2 = (const float2*)(ft + (long)row * CLD);
    float2* nc2 = (float2*)(nc + (long)row * CLD);
    float2* nt2 = (float2*)(nt + (long)row * CLD);
    const float2* d2 = (const float2*)damp;
    float sdc = 0.f, snc = 0.f, sdt = 0.f, snt = 0.f;
#pragma unroll
    for (int k = 0; k < 4; ++k) {
        int j = lane + k * 64;
        float2 dv = d2[j];
        float2 cv = c2[j], fv = fc2[j];
        float2 ncv = { dv.x * cv.x + gac * fv.x, dv.y * cv.y + gac * fv.y };
        nc2[j] = ncv;
        float dx = ncv.x - cv.x, dy = ncv.y - cv.y;
        sdc += dx * dx + dy * dy;
        snc += ncv.x * ncv.x + ncv.y * ncv.y;
        float2 tv = t2[j], gv = ft2[j];
        float2 ntv = { dv.x * tv.x + gat * gv.x, dv.y * tv.y + gat * gv.y };
        nt2[j] = ntv;
        dx = ntv.x - tv.x; dy = ntv.y - tv.y;
        sdt += dx * dx + dy * dy;
        snt += ntv.x * ntv.x + ntv.y * ntv.y;
    }
    if (lane == 0) {    // tail f2 index 256 (elements 512,513)
        float2 dv = d2[256];
        float2 cv = c2[256], fv = fc2[256];
        float2 ncv = { dv.x * cv.x + gac * fv.x, dv.y * cv.y + gac * fv.y };
        nc2[256] = ncv;
        float dx = ncv.x - cv.x, dy = ncv.y - cv.y;
        sdc += dx * dx + dy * dy;
        snc += ncv.x * ncv.x + ncv.y * ncv.y;
        float2 tv = t2[256], gv = ft2[256];
        float2 ntv = { dv.x * tv.x + gat * gv.x, dv.y * tv.y + gat * gv.y };
        nt2[256] = ntv;
        dx = ntv.x - tv.x; dy = ntv.y - tv.y;
        sdt += dx * dx + dy * dy;
        snt += ntv.x * ntv.x + ntv.y * ntv.y;
    }
#pragma unroll
    for (int o = 1; o < 64; o <<= 1) {
        sdc += __shfl_xor(sdc, o, 64);
        snc += __shfl_xor(snc, o, 64);
        sdt += __shfl_xor(sdt, o, 64);
        snt += __shfl_xor(snt, o, 64);
    }
    if (lane == 0) {
        red[wave * 4 + 0] = sqrtf(sdc);
        red[wave * 4 + 1] = sqrtf(sdt);
        red[wave * 4 + 2] = snc;
        red[wave * 4 + 3] = snt;
    }
    __syncthreads();
    if (tid < 4)
        part[tid * 1024 + blockIdx.x] =
            red[0 * 4 + tid] + red[1 * 4 + tid] + red[2 * 4 + tid] + red[3 * 4 + tid];
}

// update3 with fused convergence logic; writes state + Xct (c@0, t@TOFF).
// done-flag double-buffered by step: read scal[step], block 0 writes scal[step+1].
__global__ __launch_bounds__(256)
void update3(float* __restrict__ c, float* __restrict__ t,
             const float* __restrict__ nc, const float* __restrict__ nt,
             bf16* __restrict__ X,
             const float* __restrict__ part, float* __restrict__ scal, int step)
{
    __shared__ float red[4];
    const int tid = threadIdx.x, lane = tid & 63, wave = tid >> 6;
    {
        const float* pq = part + wave * 1024;
        float s = 0.f;
#pragma unroll
        for (int k = 0; k < 16; ++k) s += pq[lane + k * 64];
#pragma unroll
        for (int o = 1; o < 64; o <<= 1) s += __shfl_xor(s, o, 64);
        if (lane == 0) red[wave] = s;
    }
    __syncthreads();
    const float done = scal[step];
    const float dc = red[0] * (1.0f / 4096.0f);
    const float dt = red[1] * (1.0f / 4096.0f);
    const bool conv = (dc < 1e-3f) && (dt < 1e-3f);
    if (blockIdx.x == 0 && tid == 0)
        scal[step + 1] = (done != 0.f || conv) ? 1.f : 0.f;
    if (done != 0.f) return;               // frozen after convergence
    const float nrc = sqrtf(red[2]);
    const float nrt = sqrtf(red[3]);
    const float sc = conv ? 1.f : (nrc > 10.f ? 10.f / nrc : 1.f);
    const float st = conv ? 1.f : (nrt > 10.f ? 10.f / nrt : 1.f);

    const int row = blockIdx.x * 4 + wave;
    const float2* nc2 = (const float2*)(nc + (long)row * CLD);
    const float2* nt2 = (const float2*)(nt + (long)row * CLD);
    float2* c2 = (float2*)(c + (long)row * CLD);
    float2* t2 = (float2*)(t + (long)row * CLD);
    bf16* xr = X + (long)row * XCT;
#pragma unroll
    for (int k = 0; k < 5; ++k) {
        int j = lane + k * 64;
        if (k == 4 && lane > 0) break;      // only f2 idx 256 in tail
        float2 cv = nc2[j]; cv.x *= sc; cv.y *= sc;
        float2 tv = nt2[j]; tv.x *= st; tv.y *= st;
        c2[j] = cv;
        t2[j] = tv;
        *(unsigned*)(xr + j * 2)        = packbf(cv.x, cv.y);
        *(unsigned*)(xr + TOFF + j * 2) = packbf(tv.x, tv.y);
    }
}

// ---------------- host ----------------
extern "C" void kernel_launch(void* const* d_in, const int* in_sizes, int n_in,
                              void* d_out, int out_size, void* d_ws, size_t ws_size,
                              hipStream_t stream)
{
    (void)in_sizes; (void)n_in; (void)out_size; (void)ws_size;
    const float* carrier = (const float*)d_in[0];
    const float* traj    = (const float*)d_in[1];
    const float* srcp    = (const float*)d_in[2];
    const float* tgtp    = (const float*)d_in[3];
    const float* cw1 = (const float*)d_in[4];  const float* cb1 = (const float*)d_in[5];
    const float* cg  = (const float*)d_in[6];  const float* cbe = (const float*)d_in[7];
    const float* cw2 = (const float*)d_in[8];  const float* cb2 = (const float*)d_in[9];
    const float* tw1 = (const float*)d_in[10]; const float* tb1 = (const float*)d_in[11];
    const float* tg  = (const float*)d_in[12]; const float* tbe = (const float*)d_in[13];
    const float* tw2 = (const float*)d_in[14]; const float* tb2 = (const float*)d_in[15];
    const float* fd  = (const float*)d_in[16];
    const float* dw1 = (const float*)d_in[17]; const float* db1 = (const float*)d_in[18];
    const float* dw2 = (const float*)d_in[19]; const float* db2 = (const float*)d_in[20];
    const float* sw1 = (const float*)d_in[21]; const float* sb1 = (const float*)d_in[22];
    const float* sw2 = (const float*)d_in[23]; const float* sb2 = (const float*)d_in[24];
    const float* csc = (const float*)d_in[25]; const float* tsc = (const float*)d_in[26];

    char* p = (char*)d_ws;
    size_t off = 0;
    auto take = [&](size_t bytes) { size_t o = off; off += (bytes + 255) & ~(size_t)255; return o; };
    bf16*  Xct  = (bf16*) (p + take((size_t)RTOT * XCT * 2));
    bf16*  W1ct = (bf16*) (p + take((size_t)NT1 * XCT * 2));   // also absorbs gemmd overrun
    float* Y    = (float*)(p + take((size_t)RTOT * NT1 * 4));
    bf16*  H    = (bf16*) (p + take((size_t)RTOT * HLD * 2));
    bf16*  W2t  = (bf16*) (p + take((size_t)1280 * KH * 2));
    bf16*  Wdc  = (bf16*) (p + take((size_t)NDC * KDP * 2));
    float* Ybase= (float*)(p + take((size_t)8 * NT1 * 4));
    float* Ypart= (float*)(p + take((size_t)YZS * 8 * NT1 * 4));
    float* b2c  = (float*)(p + take(1280 * 4));
    float* bdc  = (float*)(p + take(NDC * 4));
    float* RT   = (float*)(p + take(640L * 512 * 4));
    float* IT   = (float*)(p + take(512L * 640 * 4));
    float* damp = (float*)(p + take(F2E * 4));
    float* cbuf = (float*)(p + take((size_t)RTOT * CLD * 4));
    float* tbuf = (float*)(p + take((size_t)RTOT * CLD * 4));
    float* ncb  = (float*)(p + take((size_t)RTOT * CLD * 4));
    float* ntb  = (float*)(p + take((size_t)RTOT * CLD * 4));
    float* fcb  = (float*)(p + take((size_t)2 * RTOT * CLD * 4)); // [fc | ft] contiguous
    float* ftb  = fcb + (size_t)RTOT * CLD;
    float* Hd   = (float*)(p + take((size_t)2 * RTOT * NDC * 4)); // stacked c|t
    float* part = (float*)(p + take(4096 * 4));
    float* scal = (float*)(p + take(1024));

    hipMemsetAsync(scal, 0, 1024, stream);      // scal[0] = done flag for step 0

    build_tables<<<2560, 256, 0, stream>>>(RT, IT);
    build_damp<<<3, 256, 0, stream>>>(damp, fd);
    ybase_part<<<dim3(9, 8, YZS), 256, 0, stream>>>(srcp, tgtp, cw1, tw1, Ypart);
    ybase_reduce<<<dim3(9, 8), 256, 0, stream>>>(Ypart, cb1, tb1, Ybase);
    w1prep<<<dim3(NT1, 5), 256, 0, stream>>>(W1ct, cw1, tw1);
    wprep<<<dim3(1280, 5), 256, 0, stream>>>(W2t, KH, cw2, 1028, 514, 0, tw2, 1028, 514, 640);
    wprep<<<dim3(NDC, 3), 256, 0, stream>>>(Wdc, KDP, dw1, 514, 257, 0, sw1, 514, 128, 257);
    bias_fill<<<5, 256, 0, stream>>>(b2c, 1280, cb2, 514, 0, tb2, 514, 640);
    bias_fill<<<2, 256, 0, stream>>>(bdc, NDC, db1, 257, 0, sb1, 128, 257);
    xpad_zero<<<RTOT, 32, 0, stream>>>(Xct);

    // rfft (fp32 DFT-matmul); RT pad rows also zero the c/t pad columns
    sgemm_bt<<<dim3(64, 10), 256, 0, stream>>>(carrier, SP, RT, SP, cbuf, CLD, 32);
    sgemm_bt<<<dim3(64, 10), 256, 0, stream>>>(traj,    SP, RT, SP, tbuf, CLD, 32);
    initconv<<<RTOT, 256, 0, stream>>>(cbuf, tbuf, Xct);

    for (int s = 0; s < 20; ++s) {
        // GEMM1: [c,t] x W1ct^T + Ybase[batch]  (BN=64 -> 1088 blocks)
        gemm_bt<0, 64><<<dim3(32, 34), 256, 0, stream>>>(Xct, XCT, W1ct, XCT, Y, NT1,
                                                         Ybase, NT1, 33, 0, 0, 0, 0);
        ln_gelu<<<2048, 256, 0, stream>>>(Y, H, cg, cbe, tg, tbe);
        // GEMM2 (both nets via z; BN=64 -> 640 blocks)
        gemm_bt<1, 64><<<dim3(32, 10, 2), 256, 0, stream>>>(H, HLD, W2t, KH, fcb, CLD,
                                                            b2c, 0, 34,
                                                            (long)KH, (long)640 * KH,
                                                            (long)RTOT * CLD, 640);
        // small-MLP hidden reads state directly from Xct (c@0 / t@TOFF via zA)
        gemm_bt<2, 64><<<dim3(32, 8, 2), 256, 0, stream>>>(Xct, XCT, Wdc, KDP, Hd, NDC,
                                                           bdc, 0, 18,
                                                           (long)TOFF, 0,
                                                           (long)RTOT * NDC, 0);
        fused_update<<<1024, 256, 0, stream>>>(Hd, dw2, db2, sw2, sb2,
                                               cbuf, tbuf, fcb, ftb, ncb, ntb,
                                               damp, csc, tsc, part);
        update3<<<1024, 256, 0, stream>>>(cbuf, tbuf, ncb, ntb, Xct, part, scal, s);
    }

    float* out = (float*)d_out;
    sgemm_bt<<<dim3(64, 8), 256, 0, stream>>>(cbuf, CLD, IT, CLD, out, SP, 40);
    sgemm_bt<<<dim3(64, 8), 256, 0, stream>>>(tbuf, CLD, IT, CLD, out + (size_t)RTOT * SP, SP, 40);
}